// Round 6
// baseline (187.762 us; speedup 1.0000x reference)
//
#include <hip/hip_runtime.h>
#include <hip/hip_bf16.h>
#include <stdint.h>

#define DEV __device__ __forceinline__

typedef short short8 __attribute__((ext_vector_type(8)));
typedef float floatx4 __attribute__((ext_vector_type(4)));

constexpr int D = 256;
constexpr int NTOK = 8192;
constexpr int MTOT = 4 * NTOK;  // 32768 rows total

DEV void gl_lds16(const void* g, void* l) {
  __builtin_amdgcn_global_load_lds(
      (const __attribute__((address_space(1))) void*)g,
      (__attribute__((address_space(3))) void*)l, 16, 0, 0);
}

DEV float bflo(uint32_t u) { return __uint_as_float(u << 16); }
DEV float bfhi(uint32_t u) { return __uint_as_float(u & 0xffff0000u); }
DEV uint32_t packbf(float a, float b) {
  uint16_t xa = __builtin_bit_cast(uint16_t, __float2bfloat16(a));
  uint16_t xb = __builtin_bit_cast(uint16_t, __float2bfloat16(b));
  return (uint32_t)xa | ((uint32_t)xb << 16);
}

// ---------------- Kernel 0: fp32 -> bf16 conversion of phi, Wq, Wk, Wv, Wo + ns zeroing -----
constexpr int PHI_E = MTOT * D;          // 8388608
constexpr int W_E = D * D;               // 65536
__global__ __launch_bounds__(256) void convert(
    const float* __restrict__ phi, const float* __restrict__ Wq,
    const float* __restrict__ Wk, const float* __restrict__ Wv,
    const float* __restrict__ Wo,
    uint32_t* __restrict__ dst, float2* __restrict__ nszero) {
  if (blockIdx.x == 0) {
    const float2 z = {0.f, 0.f};
#pragma unroll
    for (int k = 0; k < 4; k++) nszero[k * 256 + threadIdx.x] = z;
  }
  const int idx2 = blockIdx.x * 256 + threadIdx.x;  // pair index
  const int e0 = idx2 * 2;
  float2 v;
  if (e0 < PHI_E) {
    v = ((const float2*)phi)[idx2];
  } else {
    int r = e0 - PHI_E;
    if (r < W_E) v = ((const float2*)Wq)[r >> 1];
    else if (r < 2 * W_E) v = ((const float2*)Wk)[(r - W_E) >> 1];
    else if (r < 3 * W_E) v = ((const float2*)Wv)[(r - 2 * W_E) >> 1];
    else v = ((const float2*)Wo)[(r - 3 * W_E) >> 1];
  }
  dst[idx2] = packbf(v.x, v.y);
}

// ---------------- Kernel 1: fused QKV GEMM, 128x256 tile per block --------------------------
// ALL outputs row-major [tok][d]. Transposed-K/V layouts (rounds 2/5) measured SLOWER on HW
// despite better theoretical coalescing (16KB-strided writes cost more than the model says).
__global__ __launch_bounds__(256, 2) void gemm_qkv(
    const __hip_bfloat16* __restrict__ phi,
    const __hip_bfloat16* __restrict__ W16,
    const float* __restrict__ bq, const float* __restrict__ bk, const float* __restrict__ bv,
    const float* __restrict__ coords, const float* __restrict__ wts,
    const float* __restrict__ lift,
    __hip_bfloat16* __restrict__ Qb, __hip_bfloat16* __restrict__ Kb,
    __hip_bfloat16* __restrict__ Vb, float* __restrict__ nsk, float* __restrict__ nsv) {
  __shared__ __align__(16) char As[8192];
  __shared__ __align__(16) char Bs[16384];
  const int t = threadIdx.x, lane = t & 63, wid = t >> 6;
  const int wm = (wid & 1) * 64, wn = (wid >> 1) * 64;
  const int l16 = lane & 15, q4 = lane >> 4;
  // XCD swizzle: mats iterate fastest within an XCD's share -> phi tile L2-reused x3
  const int bid = blockIdx.x;
  const int g = (bid & 7) * 96 + (bid >> 3);
  const int mat = g % 3;
  const int m0 = (g / 3) * 128;
  const __hip_bfloat16* W = W16 + (size_t)mat * W_E;
  const float* bias = (mat == 0) ? bq : (mat == 1) ? bk : bv;
  __hip_bfloat16* Out = (mat == 0) ? Qb : (mat == 1) ? Kb : Vb;

  floatx4 acc[4][8] = {};

  const int srow = wid * 16 + (lane >> 2);
  const int skoff = (lane & 3) * 8;
  const __hip_bfloat16* gA = phi + (size_t)(m0 + srow) * D + skoff;
  const __hip_bfloat16* gB = W + (size_t)srow * D + skoff;
  char* lA = As + srow * 64 + skoff * 2;
  char* lB = Bs + srow * 64 + skoff * 2;

  for (int kt = 0; kt < 256; kt += 32) {
    gl_lds16(gA + kt, lA);
    gl_lds16(gA + kt + 64 * D, lA + 4096);
    gl_lds16(gB + kt, lB);
    gl_lds16(gB + kt + 64 * D, lB + 4096);
    gl_lds16(gB + kt + 128 * D, lB + 8192);
    gl_lds16(gB + kt + 192 * D, lB + 12288);
    __syncthreads();
    short8 af[4], bf8[8];
#pragma unroll
    for (int i = 0; i < 4; i++)
      af[i] = *(const short8*)(As + (wm + i * 16 + l16) * 64 + q4 * 16);
#pragma unroll
    for (int j = 0; j < 8; j++) {
      const int col = wn + (j & 3) * 16 + (j >> 2) * 128 + l16;
      bf8[j] = *(const short8*)(Bs + col * 64 + q4 * 16);
    }
#pragma unroll
    for (int i = 0; i < 4; i++)
#pragma unroll
      for (int j = 0; j < 8; j++)
        acc[i][j] = __builtin_amdgcn_mfma_f32_16x16x32_bf16(af[i], bf8[j], acc[i][j], 0, 0, 0);
    __syncthreads();
  }

  float bcol[8];
#pragma unroll
  for (int j = 0; j < 8; j++)
    bcol[j] = bias[wn + (j & 3) * 16 + (j >> 2) * 128 + l16];

  if (mat == 0) {
    float lx[4], ly[4], lz[4];
#pragma unroll
    for (int jj = 0; jj < 4; jj++) {
      const int c = wn + jj * 16 + l16;
      lx[jj] = lift[c * 3 + 0]; ly[jj] = lift[c * 3 + 1]; lz[jj] = lift[c * 3 + 2];
    }
#pragma unroll
    for (int i = 0; i < 4; i++) {
#pragma unroll
      for (int r = 0; r < 4; r++) {
        const int row = m0 + wm + i * 16 + q4 * 4 + r;
        const float cx = coords[row * 3 + 0];
        const float cy = coords[row * 3 + 1];
        const float cz = coords[row * 3 + 2];
#pragma unroll
        for (int jj = 0; jj < 4; jj++) {
          const int c = wn + jj * 16 + l16;
          const float p = cx * lx[jj] + cy * ly[jj] + cz * lz[jj];
          float s, cs;
          __sincosf(p, &s, &cs);
          const float f1 = acc[i][jj][r] + bcol[jj];
          const float f2 = acc[i][jj + 4][r] + bcol[jj + 4];
          Out[(size_t)row * D + c]       = __float2bfloat16(f1 * cs - f2 * s);
          Out[(size_t)row * D + c + 128] = __float2bfloat16(f1 * s + f2 * cs);
        }
      }
    }
  } else {
    const int b = m0 >> 13;
    float* ns = (mat == 1) ? nsk : nsv;
    float colsum[8] = {};
#pragma unroll
    for (int i = 0; i < 4; i++) {
#pragma unroll
      for (int r = 0; r < 4; r++) {
        const int row = m0 + wm + i * 16 + q4 * 4 + r;
        const float w = wts[row];
#pragma unroll
        for (int j = 0; j < 8; j++) {
          const int col = wn + (j & 3) * 16 + (j >> 2) * 128 + l16;
          const float psi = acc[i][j][r] + bcol[j];
          Out[(size_t)row * D + col] = __float2bfloat16(psi);
          colsum[j] += w * psi * psi;
        }
      }
    }
#pragma unroll
    for (int j = 0; j < 8; j++) {
      float s = colsum[j];
      s += __shfl_xor(s, 16);
      s += __shfl_xor(s, 32);
      if (q4 == 0) {
        const int col = wn + (j & 3) * 16 + (j >> 2) * 128 + l16;
        atomicAdd(&ns[b * D + col], s);
      }
    }
  }
}

// ---------------- Kernel 2: K pointwise (norm + rotary + weight), in-place on row-major K ---
__global__ __launch_bounds__(256) void kpoint(
    __hip_bfloat16* __restrict__ Kb, const float* __restrict__ coords,
    const float* __restrict__ wts, const float* __restrict__ lift,
    const float* __restrict__ nsk) {
  const int t = threadIdx.x;
  const int j = t & 63, rloc = t >> 6;
  const int r0 = blockIdx.x * 128;
  const int b = r0 >> 13;
  const int j0 = 2 * j, j1 = 2 * j + 1;
  const float lx0 = lift[j0 * 3 + 0], ly0 = lift[j0 * 3 + 1], lz0 = lift[j0 * 3 + 2];
  const float lx1 = lift[j1 * 3 + 0], ly1 = lift[j1 * 3 + 1], lz1 = lift[j1 * 3 + 2];
  const int nb = b * D;
  const float ik0 = rsqrtf(nsk[nb + j0] + 1e-5f);
  const float ik1 = rsqrtf(nsk[nb + j1] + 1e-5f);
  const float ik2 = rsqrtf(nsk[nb + 128 + j0] + 1e-5f);
  const float ik3 = rsqrtf(nsk[nb + 128 + j1] + 1e-5f);
  uint32_t* K32 = (uint32_t*)Kb;
  for (int it = 0; it < 32; it++) {
    const size_t row = (size_t)r0 + it * 4 + rloc;
    const float cx = coords[row * 3 + 0];
    const float cy = coords[row * 3 + 1];
    const float cz = coords[row * 3 + 2];
    const float p0 = cx * lx0 + cy * ly0 + cz * lz0;
    const float p1 = cx * lx1 + cy * ly1 + cz * lz1;
    float s0, c0, s1, c1;
    __sincosf(p0, &s0, &c0);
    __sincosf(p1, &s1, &c1);
    const float w = wts[row];
    const size_t base = row * 128;
    const uint32_t klo = K32[base + j], khi = K32[base + 64 + j];
    const float k1a = bflo(klo) * ik0, k1b = bfhi(klo) * ik1;
    const float k2a = bflo(khi) * ik2, k2b = bfhi(khi) * ik3;
    K32[base + j]      = packbf((k1a * c0 - k2a * s0) * w, (k1b * c1 - k2b * s1) * w);
    K32[base + 64 + j] = packbf((k1a * s0 + k2a * c0) * w, (k1b * s1 + k2b * c1) * w);
  }
}

// ---------------- Kernel 3: part[chunk][b] partial K^T V, transposed-LDS MFMA ---------------
// Row-major token-major inputs; LDS layout [e][token] rows padded to 80B -> ds_read_b128.
// 16 chunks x 512 tokens (halved from 32: part shrinks 16->8 MB).
__global__ __launch_bounds__(256, 2) void gemm_tn(
    const __hip_bfloat16* __restrict__ Kwb, const __hip_bfloat16* __restrict__ Vb,
    __hip_bfloat16* __restrict__ part) {
  __shared__ __align__(16) char Asm[128 * 80];
  __shared__ __align__(16) char Bsm[128 * 80];
  const int t = threadIdx.x, lane = t & 63, wid = t >> 6;
  const int wm = (wid & 1) * 64, wn = (wid >> 1) * 64;
  const int l16 = lane & 15, q4 = lane >> 4;
  const int chunk = blockIdx.x, ed = blockIdx.y, b = blockIdx.z;
  const int d0 = (ed >> 1) * 128, e0 = (ed & 1) * 128;
  const uint32_t* A32 = (const uint32_t*)Kwb;
  const uint32_t* B32 = (const uint32_t*)Vb;
  // staging assignment: token-pair np (xor-permuted for conflict-free LDS writes), col e2
  const int s_np = (((t & 3) | ((t >> 6) << 2)) ^ ((t >> 4) & 3));  // 0..15
  const int s_e2lo = (t >> 2) & 15;                                  // + 16*r -> 0..63
  floatx4 acc[4][4] = {};
  for (int nt = 0; nt < 512; nt += 32) {
    const int nbase = chunk * 512 + nt;
    const size_t tokbase = ((size_t)b * NTOK + nbase + 2 * s_np) * 128;
#pragma unroll
    for (int r = 0; r < 4; r++) {
      const int e2 = s_e2lo + r * 16;
      {
        const uint32_t a0 = A32[tokbase + (d0 >> 1) + e2];
        const uint32_t a1 = A32[tokbase + 128 + (d0 >> 1) + e2];
        *(uint32_t*)(Asm + (2 * e2) * 80 + 4 * s_np)     = (a0 & 0xffffu) | (a1 << 16);
        *(uint32_t*)(Asm + (2 * e2 + 1) * 80 + 4 * s_np) = (a0 >> 16) | (a1 & 0xffff0000u);
      }
      {
        const uint32_t b0 = B32[tokbase + (e0 >> 1) + e2];
        const uint32_t b1 = B32[tokbase + 128 + (e0 >> 1) + e2];
        *(uint32_t*)(Bsm + (2 * e2) * 80 + 4 * s_np)     = (b0 & 0xffffu) | (b1 << 16);
        *(uint32_t*)(Bsm + (2 * e2 + 1) * 80 + 4 * s_np) = (b0 >> 16) | (b1 & 0xffff0000u);
      }
    }
    __syncthreads();
    short8 af[4], bf8[4];
#pragma unroll
    for (int i = 0; i < 4; i++) {
      af[i]  = *(const short8*)(Asm + (wm + i * 16 + l16) * 80 + q4 * 16);
      bf8[i] = *(const short8*)(Bsm + (wn + i * 16 + l16) * 80 + q4 * 16);
    }
#pragma unroll
    for (int i = 0; i < 4; i++)
#pragma unroll
      for (int j = 0; j < 4; j++)
        acc[i][j] = __builtin_amdgcn_mfma_f32_16x16x32_bf16(af[i], bf8[j], acc[i][j], 0, 0, 0);
    __syncthreads();
  }
  __hip_bfloat16* pt = part + (((size_t)(chunk * 4 + b)) << 16);
#pragma unroll
  for (int j = 0; j < 4; j++) {
    const int cg = e0 + wn + j * 16 + l16;          // V column (e)
#pragma unroll
    for (int i = 0; i < 4; i++) {
      const int rg = d0 + wm + i * 16 + q4 * 4;     // K column (d)
#pragma unroll
      for (int r = 0; r < 4; r++)
        pt[(rg + r) * 256 + cg] = __float2bfloat16(acc[i][j][r]);
    }
  }
}

// ---------------- Kernel 4: Ps[b][d][e] = bf16( iv[e] * sum_chunks part[chunk][b] ) ---------
__global__ __launch_bounds__(256) void reduce_kvt(const uint32_t* __restrict__ part,
                                                  uint32_t* __restrict__ Ps,
                                                  const float* __restrict__ nsv) {
  const int flat2 = blockIdx.x * 256 + threadIdx.x;  // dword index over [4][32768]
  const int b = flat2 >> 15;
  const int off = flat2 & 32767;
  const int es = (off & 127) * 2;                    // e column pair
  float sx = 0, sy = 0;
#pragma unroll
  for (int c = 0; c < 16; c++) {
    const uint32_t u = part[(((size_t)(c * 4 + b)) << 15) + off];
    sx += bflo(u); sy += bfhi(u);
  }
  const float iv0 = rsqrtf(nsv[b * D + es] + 1e-5f);
  const float iv1 = rsqrtf(nsv[b * D + es + 1] + 1e-5f);
  Ps[flat2] = packbf(sx * iv0, sy * iv1);
}

// ---------------- Kernel 4b: MT[b][j][k] = bf16( sum_e Wo16[j,e] * Ps[b][k,e] ) -------------
__global__ __launch_bounds__(256, 2) void gemm_mt(
    const __hip_bfloat16* __restrict__ Wo16, const __hip_bfloat16* __restrict__ Ps,
    __hip_bfloat16* __restrict__ MT) {
  __shared__ __align__(16) char As[8192];
  __shared__ __align__(16) char Bs[8192];
  const int t = threadIdx.x, lane = t & 63, wid = t >> 6;
  const int wm = (wid & 1) * 64, wn = (wid >> 1) * 64;
  const int l16 = lane & 15, q4 = lane >> 4;
  const int m0 = blockIdx.x * 128, n0 = blockIdx.y * 128, b = blockIdx.z;
  const __hip_bfloat16* Bm = Ps + ((size_t)b << 16);
  floatx4 acc[4][4] = {};
  const int srow = wid * 16 + (lane >> 2);
  const int skoff = (lane & 3) * 8;
  const __hip_bfloat16* gA = Wo16 + (size_t)(m0 + srow) * D + skoff;
  const __hip_bfloat16* gB = Bm + (size_t)(n0 + srow) * D + skoff;
  char* lA = As + srow * 64 + skoff * 2;
  char* lB = Bs + srow * 64 + skoff * 2;
  for (int kt = 0; kt < 256; kt += 32) {
    gl_lds16(gA + kt, lA);
    gl_lds16(gA + kt + 64 * D, lA + 4096);
    gl_lds16(gB + kt, lB);
    gl_lds16(gB + kt + 64 * D, lB + 4096);
    __syncthreads();
    short8 af[4], bf8[4];
#pragma unroll
    for (int i = 0; i < 4; i++) {
      af[i]  = *(const short8*)(As + (wm + i * 16 + l16) * 64 + q4 * 16);
      bf8[i] = *(const short8*)(Bs + (wn + i * 16 + l16) * 64 + q4 * 16);
    }
#pragma unroll
    for (int i = 0; i < 4; i++)
#pragma unroll
      for (int j = 0; j < 4; j++)
        acc[i][j] = __builtin_amdgcn_mfma_f32_16x16x32_bf16(af[i], bf8[j], acc[i][j], 0, 0, 0);
    __syncthreads();
  }
  __hip_bfloat16* Ob = MT + ((size_t)b << 16);
#pragma unroll
  for (int j = 0; j < 4; j++) {
    const int colg = n0 + wn + j * 16 + l16;
#pragma unroll
    for (int i = 0; i < 4; i++) {
      const int rowg = m0 + wm + i * 16 + q4 * 4;
#pragma unroll
      for (int r = 0; r < 4; r++)
        Ob[(size_t)(rowg + r) * D + colg] = __float2bfloat16(acc[i][j][r]);
    }
  }
}

// ---------------- Kernel 5: out = q_rot @ MT^T + bo  (fp32 out to d_out) --------------------
__global__ __launch_bounds__(256, 2) void gemm_out(
    const __hip_bfloat16* __restrict__ A, const __hip_bfloat16* __restrict__ Pm,
    const float* __restrict__ bo, float* __restrict__ Og) {
  __shared__ __align__(16) char As[8192];
  __shared__ __align__(16) char Bs[8192];
  const int t = threadIdx.x, lane = t & 63, wid = t >> 6;
  const int wm = (wid & 1) * 64, wn = (wid >> 1) * 64;
  const int l16 = lane & 15, q4 = lane >> 4;
  const int m0 = blockIdx.x * 128, n0 = blockIdx.y * 128;
  const int b = m0 >> 13;
  const __hip_bfloat16* W = Pm + ((size_t)b << 16);
  floatx4 acc[4][4] = {};
  const int srow = wid * 16 + (lane >> 2);
  const int skoff = (lane & 3) * 8;
  const __hip_bfloat16* gA = A + (size_t)(m0 + srow) * D + skoff;
  const __hip_bfloat16* gB = W + (size_t)(n0 + srow) * D + skoff;
  char* lA = As + srow * 64 + skoff * 2;
  char* lB = Bs + srow * 64 + skoff * 2;
  for (int kt = 0; kt < 256; kt += 32) {
    gl_lds16(gA + kt, lA);
    gl_lds16(gA + kt + 64 * D, lA + 4096);
    gl_lds16(gB + kt, lB);
    gl_lds16(gB + kt + 64 * D, lB + 4096);
    __syncthreads();
    short8 af[4], bf8[4];
#pragma unroll
    for (int i = 0; i < 4; i++) {
      af[i]  = *(const short8*)(As + (wm + i * 16 + l16) * 64 + q4 * 16);
      bf8[i] = *(const short8*)(Bs + (wn + i * 16 + l16) * 64 + q4 * 16);
    }
#pragma unroll
    for (int i = 0; i < 4; i++)
#pragma unroll
      for (int j = 0; j < 4; j++)
        acc[i][j] = __builtin_amdgcn_mfma_f32_16x16x32_bf16(af[i], bf8[j], acc[i][j], 0, 0, 0);
    __syncthreads();
  }
#pragma unroll
  for (int j = 0; j < 4; j++) {
    const int colg = n0 + wn + j * 16 + l16;
    const float bb = bo[colg];
#pragma unroll
    for (int i = 0; i < 4; i++) {
      const int rowg = m0 + wm + i * 16 + q4 * 4;
#pragma unroll
      for (int r = 0; r < 4; r++)
        Og[(size_t)(rowg + r) * D + colg] = acc[i][j][r] + bb;
    }
  }
}

extern "C" void kernel_launch(void* const* d_in, const int* in_sizes, int n_in,
                              void* d_out, int out_size, void* d_ws, size_t ws_size,
                              hipStream_t stream) {
  const float* phi    = (const float*)d_in[0];
  const float* coords = (const float*)d_in[1];
  const float* wts    = (const float*)d_in[2];
  const float* bq     = (const float*)d_in[4];
  const float* bk     = (const float*)d_in[6];
  const float* bv     = (const float*)d_in[8];
  const float* Wo     = (const float*)d_in[9];
  const float* bo     = (const float*)d_in[10];
  const float* lift   = (const float*)d_in[11];

  char* ws = (char*)d_ws;
  __hip_bfloat16* phi16 = (__hip_bfloat16*)ws;                 // 16 MiB
  __hip_bfloat16* W16   = (__hip_bfloat16*)(ws + 16777216);    // 4 x 128 KiB (Wq,Wk,Wv,Wo)
  const size_t QOFF = 17301504;
  const size_t SZ = (size_t)MTOT * D * 2;  // 16 MiB per bf16 buffer
  __hip_bfloat16* Qb = (__hip_bfloat16*)(ws + QOFF);
  __hip_bfloat16* Kb = (__hip_bfloat16*)(ws + QOFF + SZ);      // row-major [tok][d]
  __hip_bfloat16* Vb = (__hip_bfloat16*)(ws + QOFF + 2 * SZ);  // row-major [tok][d]
  const size_t NOFF = QOFF + 3 * SZ;
  float* nsk = (float*)(ws + NOFF);
  float* nsv = (float*)(ws + NOFF + 4096);
  __hip_bfloat16* part = (__hip_bfloat16*)(ws + NOFF + 8192);                 // 8 MiB bf16
  __hip_bfloat16* Ps   = (__hip_bfloat16*)(ws + NOFF + 8192 + 16777216);      // 512 KiB
  __hip_bfloat16* MT   = (__hip_bfloat16*)(ws + NOFF + 8192 + 16777216 + 524288);  // 512 KiB

  convert<<<16896, 256, 0, stream>>>(phi, (const float*)d_in[3], (const float*)d_in[5],
                                     (const float*)d_in[7], Wo,
                                     (uint32_t*)ws, (float2*)(ws + NOFF));
  gemm_qkv<<<768, 256, 0, stream>>>(phi16, W16, bq, bk, bv, coords, wts, lift,
                                    Qb, Kb, Vb, nsk, nsv);
  kpoint<<<256, 256, 0, stream>>>(Kb, coords, wts, lift, nsk);
  gemm_tn<<<dim3(16, 4, 4), 256, 0, stream>>>(Kb, Vb, part);
  reduce_kvt<<<512, 256, 0, stream>>>((const uint32_t*)part, (uint32_t*)Ps, nsv);
  gemm_mt<<<dim3(2, 2, 4), 256, 0, stream>>>(W16 + 3 * W_E, Ps, MT);
  gemm_out<<<dim3(256, 2), 256, 0, stream>>>(Qb, MT, bo, (float*)d_out);
}

// Round 7
// 180.892 us; speedup vs baseline: 1.0380x; 1.0380x over previous
//
#include <hip/hip_runtime.h>
#include <hip/hip_bf16.h>
#include <stdint.h>

#define DEV __device__ __forceinline__

typedef short short8 __attribute__((ext_vector_type(8)));
typedef float floatx4 __attribute__((ext_vector_type(4)));
typedef uint32_t uint32x4 __attribute__((ext_vector_type(4)));

constexpr int D = 256;
constexpr int NTOK = 8192;
constexpr int MTOT = 4 * NTOK;  // 32768 rows total

DEV void gl_lds16(const void* g, void* l) {
  __builtin_amdgcn_global_load_lds(
      (const __attribute__((address_space(1))) void*)g,
      (__attribute__((address_space(3))) void*)l, 16, 0, 0);
}

DEV float bflo(uint32_t u) { return __uint_as_float(u << 16); }
DEV float bfhi(uint32_t u) { return __uint_as_float(u & 0xffff0000u); }
DEV uint32_t packbf(float a, float b) {
  uint16_t xa = __builtin_bit_cast(uint16_t, __float2bfloat16(a));
  uint16_t xb = __builtin_bit_cast(uint16_t, __float2bfloat16(b));
  return (uint32_t)xa | ((uint32_t)xb << 16);
}

constexpr int W_E = D * D;               // 65536

// ---------------- Kernel 0: fp32 -> bf16 conversion of Wq, Wk, Wv, Wo + ns zeroing ----------
// phi conversion is FUSED into gemm_qkv staging (saves its 48 MB pass).
__global__ __launch_bounds__(256) void convert_w(
    const float* __restrict__ Wq, const float* __restrict__ Wk,
    const float* __restrict__ Wv, const float* __restrict__ Wo,
    uint32_t* __restrict__ dst, float2* __restrict__ nszero) {
  if (blockIdx.x == 0) {
    const float2 z = {0.f, 0.f};
#pragma unroll
    for (int k = 0; k < 4; k++) nszero[k * 256 + threadIdx.x] = z;
  }
  const int p = blockIdx.x * 256 + threadIdx.x;  // pair index over 4 * 32768
  const int m = p >> 15;
  const int q = p & 32767;
  const float2* src = (m == 0) ? (const float2*)Wq : (m == 1) ? (const float2*)Wk
                    : (m == 2) ? (const float2*)Wv : (const float2*)Wo;
  const float2 v = src[q];
  dst[p] = packbf(v.x, v.y);
}

// ---------------- Kernel 1: fused QKV GEMM, 128x256 tile per block --------------------------
// A (phi) is read fp32 and converted to bf16 in-register during staging.
// ALL outputs row-major [tok][d]. (Transposed layouts measured slower — rounds 2/5.)
__global__ __launch_bounds__(256, 2) void gemm_qkv(
    const float* __restrict__ phi,
    const __hip_bfloat16* __restrict__ W16,
    const float* __restrict__ bq, const float* __restrict__ bk, const float* __restrict__ bv,
    const float* __restrict__ coords, const float* __restrict__ wts,
    const float* __restrict__ lift,
    __hip_bfloat16* __restrict__ Qb, __hip_bfloat16* __restrict__ Kb,
    __hip_bfloat16* __restrict__ Vb, float* __restrict__ nsk, float* __restrict__ nsv) {
  __shared__ __align__(16) char As[8192];
  __shared__ __align__(16) char Bs[16384];
  const int t = threadIdx.x, lane = t & 63, wid = t >> 6;
  const int wm = (wid & 1) * 64, wn = (wid >> 1) * 64;
  const int l16 = lane & 15, q4 = lane >> 4;
  // XCD swizzle: mats iterate fastest within an XCD's share -> phi tile L2-reused x3
  const int bid = blockIdx.x;
  const int g = (bid & 7) * 96 + (bid >> 3);
  const int mat = g % 3;
  const int m0 = (g / 3) * 128;
  const __hip_bfloat16* W = W16 + (size_t)mat * W_E;
  const float* bias = (mat == 0) ? bq : (mat == 1) ? bk : bv;
  __hip_bfloat16* Out = (mat == 0) ? Qb : (mat == 1) ? Kb : Vb;

  floatx4 acc[4][8] = {};

  const int srow = wid * 16 + (lane >> 2);
  const int skoff = (lane & 3) * 8;
  const float* gAf = phi + (size_t)(m0 + srow) * D + skoff;   // fp32 source
  const __hip_bfloat16* gB = W + (size_t)srow * D + skoff;
  char* lA = As + srow * 64 + skoff * 2;
  char* lB = Bs + srow * 64 + skoff * 2;

  for (int kt = 0; kt < 256; kt += 32) {
    // issue fp32 A loads (VGPR round-trip, converted below)
    const float4 x0 = *(const float4*)(gAf + kt);
    const float4 x1 = *(const float4*)(gAf + kt + 4);
    const float4 y0 = *(const float4*)(gAf + kt + 64 * D);
    const float4 y1 = *(const float4*)(gAf + kt + 64 * D + 4);
    // async B staging (weights, already bf16)
    gl_lds16(gB + kt, lB);
    gl_lds16(gB + kt + 64 * D, lB + 4096);
    gl_lds16(gB + kt + 128 * D, lB + 8192);
    gl_lds16(gB + kt + 192 * D, lB + 12288);
    // convert + write A (wave's 64x16B writes are contiguous 1KB -> 2-way alias, free)
    uint32x4 pa, pb;
    pa[0] = packbf(x0.x, x0.y); pa[1] = packbf(x0.z, x0.w);
    pa[2] = packbf(x1.x, x1.y); pa[3] = packbf(x1.z, x1.w);
    pb[0] = packbf(y0.x, y0.y); pb[1] = packbf(y0.z, y0.w);
    pb[2] = packbf(y1.x, y1.y); pb[3] = packbf(y1.z, y1.w);
    *(uint32x4*)lA = pa;
    *(uint32x4*)(lA + 4096) = pb;
    __syncthreads();
    short8 af[4], bf8[8];
#pragma unroll
    for (int i = 0; i < 4; i++)
      af[i] = *(const short8*)(As + (wm + i * 16 + l16) * 64 + q4 * 16);
#pragma unroll
    for (int j = 0; j < 8; j++) {
      const int col = wn + (j & 3) * 16 + (j >> 2) * 128 + l16;
      bf8[j] = *(const short8*)(Bs + col * 64 + q4 * 16);
    }
#pragma unroll
    for (int i = 0; i < 4; i++)
#pragma unroll
      for (int j = 0; j < 8; j++)
        acc[i][j] = __builtin_amdgcn_mfma_f32_16x16x32_bf16(af[i], bf8[j], acc[i][j], 0, 0, 0);
    __syncthreads();
  }

  float bcol[8];
#pragma unroll
  for (int j = 0; j < 8; j++)
    bcol[j] = bias[wn + (j & 3) * 16 + (j >> 2) * 128 + l16];

  if (mat == 0) {
    float lx[4], ly[4], lz[4];
#pragma unroll
    for (int jj = 0; jj < 4; jj++) {
      const int c = wn + jj * 16 + l16;
      lx[jj] = lift[c * 3 + 0]; ly[jj] = lift[c * 3 + 1]; lz[jj] = lift[c * 3 + 2];
    }
#pragma unroll
    for (int i = 0; i < 4; i++) {
#pragma unroll
      for (int r = 0; r < 4; r++) {
        const int row = m0 + wm + i * 16 + q4 * 4 + r;
        const float cx = coords[row * 3 + 0];
        const float cy = coords[row * 3 + 1];
        const float cz = coords[row * 3 + 2];
#pragma unroll
        for (int jj = 0; jj < 4; jj++) {
          const int c = wn + jj * 16 + l16;
          const float p = cx * lx[jj] + cy * ly[jj] + cz * lz[jj];
          float s, cs;
          __sincosf(p, &s, &cs);
          const float f1 = acc[i][jj][r] + bcol[jj];
          const float f2 = acc[i][jj + 4][r] + bcol[jj + 4];
          Out[(size_t)row * D + c]       = __float2bfloat16(f1 * cs - f2 * s);
          Out[(size_t)row * D + c + 128] = __float2bfloat16(f1 * s + f2 * cs);
        }
      }
    }
  } else {
    const int b = m0 >> 13;
    float* ns = (mat == 1) ? nsk : nsv;
    float colsum[8] = {};
#pragma unroll
    for (int i = 0; i < 4; i++) {
#pragma unroll
      for (int r = 0; r < 4; r++) {
        const int row = m0 + wm + i * 16 + q4 * 4 + r;
        const float w = wts[row];
#pragma unroll
        for (int j = 0; j < 8; j++) {
          const int col = wn + (j & 3) * 16 + (j >> 2) * 128 + l16;
          const float psi = acc[i][j][r] + bcol[j];
          Out[(size_t)row * D + col] = __float2bfloat16(psi);
          colsum[j] += w * psi * psi;
        }
      }
    }
#pragma unroll
    for (int j = 0; j < 8; j++) {
      float s = colsum[j];
      s += __shfl_xor(s, 16);
      s += __shfl_xor(s, 32);
      if (q4 == 0) {
        const int col = wn + (j & 3) * 16 + (j >> 2) * 128 + l16;
        atomicAdd(&ns[b * D + col], s);
      }
    }
  }
}

// ---------------- Kernel 2: K pointwise (norm + rotary + weight), in-place on row-major K ---
__global__ __launch_bounds__(256) void kpoint(
    __hip_bfloat16* __restrict__ Kb, const float* __restrict__ coords,
    const float* __restrict__ wts, const float* __restrict__ lift,
    const float* __restrict__ nsk) {
  const int t = threadIdx.x;
  const int j = t & 63, rloc = t >> 6;
  const int r0 = blockIdx.x * 128;
  const int b = r0 >> 13;
  const int j0 = 2 * j, j1 = 2 * j + 1;
  const float lx0 = lift[j0 * 3 + 0], ly0 = lift[j0 * 3 + 1], lz0 = lift[j0 * 3 + 2];
  const float lx1 = lift[j1 * 3 + 0], ly1 = lift[j1 * 3 + 1], lz1 = lift[j1 * 3 + 2];
  const int nb = b * D;
  const float ik0 = rsqrtf(nsk[nb + j0] + 1e-5f);
  const float ik1 = rsqrtf(nsk[nb + j1] + 1e-5f);
  const float ik2 = rsqrtf(nsk[nb + 128 + j0] + 1e-5f);
  const float ik3 = rsqrtf(nsk[nb + 128 + j1] + 1e-5f);
  uint32_t* K32 = (uint32_t*)Kb;
  for (int it = 0; it < 32; it++) {
    const size_t row = (size_t)r0 + it * 4 + rloc;
    const float cx = coords[row * 3 + 0];
    const float cy = coords[row * 3 + 1];
    const float cz = coords[row * 3 + 2];
    const float p0 = cx * lx0 + cy * ly0 + cz * lz0;
    const float p1 = cx * lx1 + cy * ly1 + cz * lz1;
    float s0, c0, s1, c1;
    __sincosf(p0, &s0, &c0);
    __sincosf(p1, &s1, &c1);
    const float w = wts[row];
    const size_t base = row * 128;
    const uint32_t klo = K32[base + j], khi = K32[base + 64 + j];
    const float k1a = bflo(klo) * ik0, k1b = bfhi(klo) * ik1;
    const float k2a = bflo(khi) * ik2, k2b = bfhi(khi) * ik3;
    K32[base + j]      = packbf((k1a * c0 - k2a * s0) * w, (k1b * c1 - k2b * s1) * w);
    K32[base + 64 + j] = packbf((k1a * s0 + k2a * c0) * w, (k1b * s1 + k2b * c1) * w);
  }
}

// ---------------- Kernel 3: part[chunk][b] partial K^T V, transposed-LDS MFMA ---------------
// r1-proven config: 32 chunks x 256 tokens, 1-D grid 512 with XCD swizzle,
// bit-surgery staging into 80B-padded [e][token] LDS rows (ds_read_b128 fragments).
__global__ __launch_bounds__(256, 2) void gemm_tn(
    const __hip_bfloat16* __restrict__ Kwb, const __hip_bfloat16* __restrict__ Vb,
    __hip_bfloat16* __restrict__ part) {
  __shared__ __align__(16) char Asm[128 * 80];
  __shared__ __align__(16) char Bsm[128 * 80];
  const int t = threadIdx.x, lane = t & 63, wid = t >> 6;
  const int wm = (wid & 1) * 64, wn = (wid >> 1) * 64;
  const int l16 = lane & 15, q4 = lane >> 4;
  // swizzle: the 4 ed-blocks of one (chunk,b) are adjacent -> L2-share K/V tiles
  const int bid = blockIdx.x;
  const int g = (bid & 7) * 64 + (bid >> 3);
  const int ed = g & 3, rest = g >> 2;
  const int chunk = rest & 31, b = rest >> 5;
  const int d0 = (ed >> 1) * 128, e0 = (ed & 1) * 128;
  const uint32_t* A32 = (const uint32_t*)Kwb;
  const uint32_t* B32 = (const uint32_t*)Vb;
  const int s_np = (((t & 3) | ((t >> 6) << 2)) ^ ((t >> 4) & 3));  // 0..15
  const int s_e2lo = (t >> 2) & 15;                                  // + 16*r -> 0..63
  floatx4 acc[4][4] = {};
  for (int nt = 0; nt < 256; nt += 32) {
    const int nbase = chunk * 256 + nt;
    const size_t tokbase = ((size_t)b * NTOK + nbase + 2 * s_np) * 128;
#pragma unroll
    for (int r = 0; r < 4; r++) {
      const int e2 = s_e2lo + r * 16;
      {
        const uint32_t a0 = A32[tokbase + (d0 >> 1) + e2];
        const uint32_t a1 = A32[tokbase + 128 + (d0 >> 1) + e2];
        *(uint32_t*)(Asm + (2 * e2) * 80 + 4 * s_np)     = (a0 & 0xffffu) | (a1 << 16);
        *(uint32_t*)(Asm + (2 * e2 + 1) * 80 + 4 * s_np) = (a0 >> 16) | (a1 & 0xffff0000u);
      }
      {
        const uint32_t b0 = B32[tokbase + (e0 >> 1) + e2];
        const uint32_t b1 = B32[tokbase + 128 + (e0 >> 1) + e2];
        *(uint32_t*)(Bsm + (2 * e2) * 80 + 4 * s_np)     = (b0 & 0xffffu) | (b1 << 16);
        *(uint32_t*)(Bsm + (2 * e2 + 1) * 80 + 4 * s_np) = (b0 >> 16) | (b1 & 0xffff0000u);
      }
    }
    __syncthreads();
    short8 af[4], bf8[4];
#pragma unroll
    for (int i = 0; i < 4; i++) {
      af[i]  = *(const short8*)(Asm + (wm + i * 16 + l16) * 80 + q4 * 16);
      bf8[i] = *(const short8*)(Bsm + (wn + i * 16 + l16) * 80 + q4 * 16);
    }
#pragma unroll
    for (int i = 0; i < 4; i++)
#pragma unroll
      for (int j = 0; j < 4; j++)
        acc[i][j] = __builtin_amdgcn_mfma_f32_16x16x32_bf16(af[i], bf8[j], acc[i][j], 0, 0, 0);
    __syncthreads();
  }
  __hip_bfloat16* pt = part + (((size_t)(chunk * 4 + b)) << 16);
#pragma unroll
  for (int i = 0; i < 4; i++) {
#pragma unroll
    for (int r = 0; r < 4; r++) {
      const int rg = d0 + wm + i * 16 + q4 * 4 + r;   // K column (d)
#pragma unroll
      for (int j = 0; j < 4; j++) {
        const int cg = e0 + wn + j * 16 + l16;        // V column (e)
        pt[rg * 256 + cg] = __float2bfloat16(acc[i][j][r]);
      }
    }
  }
}

// ---------------- Kernel 4: Ps[b][d][e] = bf16( iv[e] * sum_chunks part[chunk][b] ) ---------
__global__ __launch_bounds__(256) void reduce_kvt(const uint32_t* __restrict__ part,
                                                  uint32_t* __restrict__ Ps,
                                                  const float* __restrict__ nsv) {
  const int flat2 = blockIdx.x * 256 + threadIdx.x;  // dword index over [4][32768]
  const int b = flat2 >> 15;
  const int off = flat2 & 32767;
  const int es = (off & 127) * 2;                    // e column pair
  float sx = 0, sy = 0;
#pragma unroll
  for (int c = 0; c < 32; c++) {
    const uint32_t u = part[(((size_t)(c * 4 + b)) << 15) + off];
    sx += bflo(u); sy += bfhi(u);
  }
  const float iv0 = rsqrtf(nsv[b * D + es] + 1e-5f);
  const float iv1 = rsqrtf(nsv[b * D + es + 1] + 1e-5f);
  Ps[flat2] = packbf(sx * iv0, sy * iv1);
}

// ---------------- Kernel 4b: MT[b][j][k] = bf16( sum_e Wo16[j,e] * Ps[b][k,e] ) -------------
__global__ __launch_bounds__(256, 2) void gemm_mt(
    const __hip_bfloat16* __restrict__ Wo16, const __hip_bfloat16* __restrict__ Ps,
    __hip_bfloat16* __restrict__ MT) {
  __shared__ __align__(16) char As[8192];
  __shared__ __align__(16) char Bs[8192];
  const int t = threadIdx.x, lane = t & 63, wid = t >> 6;
  const int wm = (wid & 1) * 64, wn = (wid >> 1) * 64;
  const int l16 = lane & 15, q4 = lane >> 4;
  const int m0 = blockIdx.x * 128, n0 = blockIdx.y * 128, b = blockIdx.z;
  const __hip_bfloat16* Bm = Ps + ((size_t)b << 16);
  floatx4 acc[4][4] = {};
  const int srow = wid * 16 + (lane >> 2);
  const int skoff = (lane & 3) * 8;
  const __hip_bfloat16* gA = Wo16 + (size_t)(m0 + srow) * D + skoff;
  const __hip_bfloat16* gB = Bm + (size_t)(n0 + srow) * D + skoff;
  char* lA = As + srow * 64 + skoff * 2;
  char* lB = Bs + srow * 64 + skoff * 2;
  for (int kt = 0; kt < 256; kt += 32) {
    gl_lds16(gA + kt, lA);
    gl_lds16(gA + kt + 64 * D, lA + 4096);
    gl_lds16(gB + kt, lB);
    gl_lds16(gB + kt + 64 * D, lB + 4096);
    __syncthreads();
    short8 af[4], bf8[4];
#pragma unroll
    for (int i = 0; i < 4; i++) {
      af[i]  = *(const short8*)(As + (wm + i * 16 + l16) * 64 + q4 * 16);
      bf8[i] = *(const short8*)(Bs + (wn + i * 16 + l16) * 64 + q4 * 16);
    }
#pragma unroll
    for (int i = 0; i < 4; i++)
#pragma unroll
      for (int j = 0; j < 4; j++)
        acc[i][j] = __builtin_amdgcn_mfma_f32_16x16x32_bf16(af[i], bf8[j], acc[i][j], 0, 0, 0);
    __syncthreads();
  }
  __hip_bfloat16* Ob = MT + ((size_t)b << 16);
#pragma unroll
  for (int j = 0; j < 4; j++) {
    const int colg = n0 + wn + j * 16 + l16;
#pragma unroll
    for (int i = 0; i < 4; i++) {
      const int rowg = m0 + wm + i * 16 + q4 * 4;
#pragma unroll
      for (int r = 0; r < 4; r++)
        Ob[(size_t)(rowg + r) * D + colg] = __float2bfloat16(acc[i][j][r]);
    }
  }
}

// ---------------- Kernel 5: out = q_rot @ MT^T + bo  (fp32 out to d_out) --------------------
__global__ __launch_bounds__(256, 2) void gemm_out(
    const __hip_bfloat16* __restrict__ A, const __hip_bfloat16* __restrict__ Pm,
    const float* __restrict__ bo, float* __restrict__ Og) {
  __shared__ __align__(16) char As[8192];
  __shared__ __align__(16) char Bs[8192];
  const int t = threadIdx.x, lane = t & 63, wid = t >> 6;
  const int wm = (wid & 1) * 64, wn = (wid >> 1) * 64;
  const int l16 = lane & 15, q4 = lane >> 4;
  const int m0 = blockIdx.x * 128, n0 = blockIdx.y * 128;
  const int b = m0 >> 13;
  const __hip_bfloat16* W = Pm + ((size_t)b << 16);
  floatx4 acc[4][4] = {};
  const int srow = wid * 16 + (lane >> 2);
  const int skoff = (lane & 3) * 8;
  const __hip_bfloat16* gA = A + (size_t)(m0 + srow) * D + skoff;
  const __hip_bfloat16* gB = W + (size_t)(n0 + srow) * D + skoff;
  char* lA = As + srow * 64 + skoff * 2;
  char* lB = Bs + srow * 64 + skoff * 2;
  for (int kt = 0; kt < 256; kt += 32) {
    gl_lds16(gA + kt, lA);
    gl_lds16(gA + kt + 64 * D, lA + 4096);
    gl_lds16(gB + kt, lB);
    gl_lds16(gB + kt + 64 * D, lB + 4096);
    __syncthreads();
    short8 af[4], bf8[4];
#pragma unroll
    for (int i = 0; i < 4; i++) {
      af[i]  = *(const short8*)(As + (wm + i * 16 + l16) * 64 + q4 * 16);
      bf8[i] = *(const short8*)(Bs + (wn + i * 16 + l16) * 64 + q4 * 16);
    }
#pragma unroll
    for (int i = 0; i < 4; i++)
#pragma unroll
      for (int j = 0; j < 4; j++)
        acc[i][j] = __builtin_amdgcn_mfma_f32_16x16x32_bf16(af[i], bf8[j], acc[i][j], 0, 0, 0);
    __syncthreads();
  }
#pragma unroll
  for (int j = 0; j < 4; j++) {
    const int colg = n0 + wn + j * 16 + l16;
    const float bb = bo[colg];
#pragma unroll
    for (int i = 0; i < 4; i++) {
      const int rowg = m0 + wm + i * 16 + q4 * 4;
#pragma unroll
      for (int r = 0; r < 4; r++)
        Og[(size_t)(rowg + r) * D + colg] = acc[i][j][r] + bb;
    }
  }
}

extern "C" void kernel_launch(void* const* d_in, const int* in_sizes, int n_in,
                              void* d_out, int out_size, void* d_ws, size_t ws_size,
                              hipStream_t stream) {
  const float* phi    = (const float*)d_in[0];
  const float* coords = (const float*)d_in[1];
  const float* wts    = (const float*)d_in[2];
  const float* bq     = (const float*)d_in[4];
  const float* bk     = (const float*)d_in[6];
  const float* bv     = (const float*)d_in[8];
  const float* Wo     = (const float*)d_in[9];
  const float* bo     = (const float*)d_in[10];
  const float* lift   = (const float*)d_in[11];

  char* ws = (char*)d_ws;
  __hip_bfloat16* W16   = (__hip_bfloat16*)(ws + 16777216);    // 4 x 128 KiB (Wq,Wk,Wv,Wo)
  const size_t QOFF = 17301504;
  const size_t SZ = (size_t)MTOT * D * 2;  // 16 MiB per bf16 buffer
  __hip_bfloat16* Qb = (__hip_bfloat16*)(ws + QOFF);
  __hip_bfloat16* Kb = (__hip_bfloat16*)(ws + QOFF + SZ);      // row-major [tok][d]
  __hip_bfloat16* Vb = (__hip_bfloat16*)(ws + QOFF + 2 * SZ);  // row-major [tok][d]
  const size_t NOFF = QOFF + 3 * SZ;
  float* nsk = (float*)(ws + NOFF);
  float* nsv = (float*)(ws + NOFF + 4096);
  __hip_bfloat16* part = (__hip_bfloat16*)(ws + NOFF + 8192);                 // 16 MiB bf16
  __hip_bfloat16* Ps   = (__hip_bfloat16*)(ws + NOFF + 8192 + 16777216);      // 512 KiB
  __hip_bfloat16* MT   = (__hip_bfloat16*)(ws + NOFF + 8192 + 16777216 + 524288);  // 512 KiB

  convert_w<<<512, 256, 0, stream>>>((const float*)d_in[3], (const float*)d_in[5],
                                     (const float*)d_in[7], Wo,
                                     (uint32_t*)W16, (float2*)(ws + NOFF));
  gemm_qkv<<<768, 256, 0, stream>>>(phi, W16, bq, bk, bv, coords, wts, lift,
                                    Qb, Kb, Vb, nsk, nsv);
  kpoint<<<256, 256, 0, stream>>>(Kb, coords, wts, lift, nsk);
  gemm_tn<<<512, 256, 0, stream>>>(Kb, Vb, part);
  reduce_kvt<<<512, 256, 0, stream>>>((const uint32_t*)part, (uint32_t*)Ps, nsv);
  gemm_mt<<<dim3(2, 2, 4), 256, 0, stream>>>(W16 + 3 * W_E, Ps, MT);
  gemm_out<<<dim3(256, 2), 256, 0, stream>>>(Qb, MT, bo, (float*)d_out);
}

// Round 8
// 178.137 us; speedup vs baseline: 1.0540x; 1.0155x over previous
//
#include <hip/hip_runtime.h>
#include <hip/hip_bf16.h>
#include <stdint.h>

#define DEV __device__ __forceinline__

typedef short short8 __attribute__((ext_vector_type(8)));
typedef float floatx4 __attribute__((ext_vector_type(4)));
typedef uint32_t uint32x4 __attribute__((ext_vector_type(4)));

constexpr int D = 256;
constexpr int NTOK = 8192;
constexpr int MTOT = 4 * NTOK;  // 32768 rows total

DEV void gl_lds16(const void* g, void* l) {
  __builtin_amdgcn_global_load_lds(
      (const __attribute__((address_space(1))) void*)g,
      (__attribute__((address_space(3))) void*)l, 16, 0, 0);
}

DEV float bflo(uint32_t u) { return __uint_as_float(u << 16); }
DEV float bfhi(uint32_t u) { return __uint_as_float(u & 0xffff0000u); }
DEV uint32_t packbf(float a, float b) {
  uint16_t xa = __builtin_bit_cast(uint16_t, __float2bfloat16(a));
  uint16_t xb = __builtin_bit_cast(uint16_t, __float2bfloat16(b));
  return (uint32_t)xa | ((uint32_t)xb << 16);
}

constexpr int W_E = D * D;               // 65536

// ---------------- Kernel 0: fp32 -> bf16 conversion of Wq, Wk, Wv, Wo + ns zeroing ----------
// phi conversion is FUSED into gemm_qkv staging (r7: WRITE_SIZE confirmed at ideal ~50 MB).
__global__ __launch_bounds__(256) void convert_w(
    const float* __restrict__ Wq, const float* __restrict__ Wk,
    const float* __restrict__ Wv, const float* __restrict__ Wo,
    uint32_t* __restrict__ dst, float2* __restrict__ nszero) {
  if (blockIdx.x == 0) {
    const float2 z = {0.f, 0.f};
#pragma unroll
    for (int k = 0; k < 4; k++) nszero[k * 256 + threadIdx.x] = z;
  }
  const int p = blockIdx.x * 256 + threadIdx.x;  // pair index over 4 * 32768
  const int m = p >> 15;
  const int q = p & 32767;
  const float2* src = (m == 0) ? (const float2*)Wq : (m == 1) ? (const float2*)Wk
                    : (m == 2) ? (const float2*)Wv : (const float2*)Wo;
  const float2 v = src[q];
  dst[p] = packbf(v.x, v.y);
}

// ---------------- Kernel 1: fused QKV GEMM, 128x(64+64 paired cols) tile per block ----------
// r7 post-mortem: 256-wide tile (acc[4][8], VGPR 128) gave 12-14% occupancy, latency-bound
// at 46us with all pipes <20%. Halved tile -> acc[4][4], ~100 VGPR, 4-5 blocks/CU, grid 1536.
// Column pair (c, c+128) kept inside the block so Q-rotary stays local.
__global__ __launch_bounds__(256, 4) void gemm_qkv(
    const float* __restrict__ phi,
    const __hip_bfloat16* __restrict__ W16,
    const float* __restrict__ bq, const float* __restrict__ bk, const float* __restrict__ bv,
    const float* __restrict__ coords, const float* __restrict__ wts,
    const float* __restrict__ lift,
    __hip_bfloat16* __restrict__ Qb, __hip_bfloat16* __restrict__ Kb,
    __hip_bfloat16* __restrict__ Vb, float* __restrict__ nsk, float* __restrict__ nsv) {
  __shared__ __align__(16) char As[8192];
  __shared__ __align__(16) char Bs[8192];
  const int t = threadIdx.x, lane = t & 63, wid = t >> 6;
  const int wm = (wid & 1) * 64;         // row offset
  const int wn = (wid >> 1) * 32;        // colpair offset within 64
  const int l16 = lane & 15, q4 = lane >> 4;
  // XCD swizzle: the 6 blocks (3 mats x 2 col-halves) of one m0 adjacent -> phi L2-reused x6
  const int bid = blockIdx.x;
  const int g = (bid & 7) * 192 + (bid >> 3);
  const int sub = g % 6;
  const int mat = sub >> 1;
  const int nc0 = (sub & 1) * 64;        // colpair base: cols nc0.. and nc0+128..
  const int m0 = (g / 6) * 128;
  const __hip_bfloat16* W = W16 + (size_t)mat * W_E;
  const float* bias = (mat == 0) ? bq : (mat == 1) ? bk : bv;
  __hip_bfloat16* Out = (mat == 0) ? Qb : (mat == 1) ? Kb : Vb;

  floatx4 acc[4][4] = {};

  const int srow = wid * 16 + (lane >> 2);          // 0..63
  const int skoff = (lane & 3) * 8;
  const float* gAf = phi + (size_t)(m0 + srow) * D + skoff;   // fp32 source
  const __hip_bfloat16* gB = W + (size_t)(nc0 + srow) * D + skoff;
  char* lA = As + srow * 64 + skoff * 2;
  char* lB = Bs + srow * 64 + skoff * 2;

  for (int kt = 0; kt < 256; kt += 32) {
    // fp32 A loads (converted below)
    const float4 x0 = *(const float4*)(gAf + kt);
    const float4 x1 = *(const float4*)(gAf + kt + 4);
    const float4 y0 = *(const float4*)(gAf + kt + 64 * D);
    const float4 y1 = *(const float4*)(gAf + kt + 64 * D + 4);
    // async B staging: lo cols (nc0+srow) and hi cols (nc0+128+srow)
    gl_lds16(gB + kt, lB);
    gl_lds16(gB + kt + 128 * D, lB + 4096);
    uint32x4 pa, pb;
    pa[0] = packbf(x0.x, x0.y); pa[1] = packbf(x0.z, x0.w);
    pa[2] = packbf(x1.x, x1.y); pa[3] = packbf(x1.z, x1.w);
    pb[0] = packbf(y0.x, y0.y); pb[1] = packbf(y0.z, y0.w);
    pb[2] = packbf(y1.x, y1.y); pb[3] = packbf(y1.z, y1.w);
    *(uint32x4*)lA = pa;
    *(uint32x4*)(lA + 4096) = pb;
    __syncthreads();
    short8 af[4], bf4[4];
#pragma unroll
    for (int i = 0; i < 4; i++)
      af[i] = *(const short8*)(As + (wm + i * 16 + l16) * 64 + q4 * 16);
#pragma unroll
    for (int j = 0; j < 4; j++) {
      const int brow = (j >> 1) * 64 + wn + (j & 1) * 16 + l16;  // lo rows 0..63, hi 64..127
      bf4[j] = *(const short8*)(Bs + brow * 64 + q4 * 16);
    }
#pragma unroll
    for (int i = 0; i < 4; i++)
#pragma unroll
      for (int j = 0; j < 4; j++)
        acc[i][j] = __builtin_amdgcn_mfma_f32_16x16x32_bf16(af[i], bf4[j], acc[i][j], 0, 0, 0);
    __syncthreads();
  }

  float bcol[4];
#pragma unroll
  for (int j = 0; j < 4; j++)
    bcol[j] = bias[nc0 + wn + (j & 1) * 16 + (j >> 1) * 128 + l16];

  if (mat == 0) {
    float lx[2], ly[2], lz[2];
#pragma unroll
    for (int jj = 0; jj < 2; jj++) {
      const int c = nc0 + wn + jj * 16 + l16;
      lx[jj] = lift[c * 3 + 0]; ly[jj] = lift[c * 3 + 1]; lz[jj] = lift[c * 3 + 2];
    }
#pragma unroll
    for (int i = 0; i < 4; i++) {
#pragma unroll
      for (int r = 0; r < 4; r++) {
        const int row = m0 + wm + i * 16 + q4 * 4 + r;
        const float cx = coords[row * 3 + 0];
        const float cy = coords[row * 3 + 1];
        const float cz = coords[row * 3 + 2];
#pragma unroll
        for (int jj = 0; jj < 2; jj++) {
          const int c = nc0 + wn + jj * 16 + l16;
          const float p = cx * lx[jj] + cy * ly[jj] + cz * lz[jj];
          float s, cs;
          __sincosf(p, &s, &cs);
          const float f1 = acc[i][jj][r] + bcol[jj];
          const float f2 = acc[i][jj + 2][r] + bcol[jj + 2];
          Out[(size_t)row * D + c]       = __float2bfloat16(f1 * cs - f2 * s);
          Out[(size_t)row * D + c + 128] = __float2bfloat16(f1 * s + f2 * cs);
        }
      }
    }
  } else {
    const int b = m0 >> 13;
    float* ns = (mat == 1) ? nsk : nsv;
    float colsum[4] = {};
#pragma unroll
    for (int i = 0; i < 4; i++) {
#pragma unroll
      for (int r = 0; r < 4; r++) {
        const int row = m0 + wm + i * 16 + q4 * 4 + r;
        const float w = wts[row];
#pragma unroll
        for (int j = 0; j < 4; j++) {
          const int col = nc0 + wn + (j & 1) * 16 + (j >> 1) * 128 + l16;
          const float psi = acc[i][j][r] + bcol[j];
          Out[(size_t)row * D + col] = __float2bfloat16(psi);
          colsum[j] += w * psi * psi;
        }
      }
    }
#pragma unroll
    for (int j = 0; j < 4; j++) {
      float s = colsum[j];
      s += __shfl_xor(s, 16);
      s += __shfl_xor(s, 32);
      if (q4 == 0) {
        const int col = nc0 + wn + (j & 1) * 16 + (j >> 1) * 128 + l16;
        atomicAdd(&ns[b * D + col], s);
      }
    }
  }
}

// ---------------- Kernel 2: K pointwise (norm + rotary + weight), in-place on row-major K ---
// 1024 blocks (was 256 = 1/CU) for TLP.
__global__ __launch_bounds__(256) void kpoint(
    __hip_bfloat16* __restrict__ Kb, const float* __restrict__ coords,
    const float* __restrict__ wts, const float* __restrict__ lift,
    const float* __restrict__ nsk) {
  const int t = threadIdx.x;
  const int j = t & 63, rloc = t >> 6;
  const int r0 = blockIdx.x * 32;
  const int b = r0 >> 13;
  const int j0 = 2 * j, j1 = 2 * j + 1;
  const float lx0 = lift[j0 * 3 + 0], ly0 = lift[j0 * 3 + 1], lz0 = lift[j0 * 3 + 2];
  const float lx1 = lift[j1 * 3 + 0], ly1 = lift[j1 * 3 + 1], lz1 = lift[j1 * 3 + 2];
  const int nb = b * D;
  const float ik0 = rsqrtf(nsk[nb + j0] + 1e-5f);
  const float ik1 = rsqrtf(nsk[nb + j1] + 1e-5f);
  const float ik2 = rsqrtf(nsk[nb + 128 + j0] + 1e-5f);
  const float ik3 = rsqrtf(nsk[nb + 128 + j1] + 1e-5f);
  uint32_t* K32 = (uint32_t*)Kb;
#pragma unroll
  for (int it = 0; it < 8; it++) {
    const size_t row = (size_t)r0 + it * 4 + rloc;
    const float cx = coords[row * 3 + 0];
    const float cy = coords[row * 3 + 1];
    const float cz = coords[row * 3 + 2];
    const float p0 = cx * lx0 + cy * ly0 + cz * lz0;
    const float p1 = cx * lx1 + cy * ly1 + cz * lz1;
    float s0, c0, s1, c1;
    __sincosf(p0, &s0, &c0);
    __sincosf(p1, &s1, &c1);
    const float w = wts[row];
    const size_t base = row * 128;
    const uint32_t klo = K32[base + j], khi = K32[base + 64 + j];
    const float k1a = bflo(klo) * ik0, k1b = bfhi(klo) * ik1;
    const float k2a = bflo(khi) * ik2, k2b = bfhi(khi) * ik3;
    K32[base + j]      = packbf((k1a * c0 - k2a * s0) * w, (k1b * c1 - k2b * s1) * w);
    K32[base + 64 + j] = packbf((k1a * s0 + k2a * c0) * w, (k1b * s1 + k2b * c1) * w);
  }
}

// ---------------- Kernel 3: part[chunk][b] partial K^T V, transposed-LDS MFMA ---------------
// r1-proven config: 32 chunks x 256 tokens, 1-D grid 512 with XCD swizzle,
// bit-surgery staging into 80B-padded [e][token] LDS rows (ds_read_b128 fragments).
__global__ __launch_bounds__(256, 2) void gemm_tn(
    const __hip_bfloat16* __restrict__ Kwb, const __hip_bfloat16* __restrict__ Vb,
    __hip_bfloat16* __restrict__ part) {
  __shared__ __align__(16) char Asm[128 * 80];
  __shared__ __align__(16) char Bsm[128 * 80];
  const int t = threadIdx.x, lane = t & 63, wid = t >> 6;
  const int wm = (wid & 1) * 64, wn = (wid >> 1) * 64;
  const int l16 = lane & 15, q4 = lane >> 4;
  const int bid = blockIdx.x;
  const int g = (bid & 7) * 64 + (bid >> 3);
  const int ed = g & 3, rest = g >> 2;
  const int chunk = rest & 31, b = rest >> 5;
  const int d0 = (ed >> 1) * 128, e0 = (ed & 1) * 128;
  const uint32_t* A32 = (const uint32_t*)Kwb;
  const uint32_t* B32 = (const uint32_t*)Vb;
  const int s_np = (((t & 3) | ((t >> 6) << 2)) ^ ((t >> 4) & 3));  // 0..15
  const int s_e2lo = (t >> 2) & 15;                                  // + 16*r -> 0..63
  floatx4 acc[4][4] = {};
  for (int nt = 0; nt < 256; nt += 32) {
    const int nbase = chunk * 256 + nt;
    const size_t tokbase = ((size_t)b * NTOK + nbase + 2 * s_np) * 128;
#pragma unroll
    for (int r = 0; r < 4; r++) {
      const int e2 = s_e2lo + r * 16;
      {
        const uint32_t a0 = A32[tokbase + (d0 >> 1) + e2];
        const uint32_t a1 = A32[tokbase + 128 + (d0 >> 1) + e2];
        *(uint32_t*)(Asm + (2 * e2) * 80 + 4 * s_np)     = (a0 & 0xffffu) | (a1 << 16);
        *(uint32_t*)(Asm + (2 * e2 + 1) * 80 + 4 * s_np) = (a0 >> 16) | (a1 & 0xffff0000u);
      }
      {
        const uint32_t b0 = B32[tokbase + (e0 >> 1) + e2];
        const uint32_t b1 = B32[tokbase + 128 + (e0 >> 1) + e2];
        *(uint32_t*)(Bsm + (2 * e2) * 80 + 4 * s_np)     = (b0 & 0xffffu) | (b1 << 16);
        *(uint32_t*)(Bsm + (2 * e2 + 1) * 80 + 4 * s_np) = (b0 >> 16) | (b1 & 0xffff0000u);
      }
    }
    __syncthreads();
    short8 af[4], bf8[4];
#pragma unroll
    for (int i = 0; i < 4; i++) {
      af[i]  = *(const short8*)(Asm + (wm + i * 16 + l16) * 80 + q4 * 16);
      bf8[i] = *(const short8*)(Bsm + (wn + i * 16 + l16) * 80 + q4 * 16);
    }
#pragma unroll
    for (int i = 0; i < 4; i++)
#pragma unroll
      for (int j = 0; j < 4; j++)
        acc[i][j] = __builtin_amdgcn_mfma_f32_16x16x32_bf16(af[i], bf8[j], acc[i][j], 0, 0, 0);
    __syncthreads();
  }
  __hip_bfloat16* pt = part + (((size_t)(chunk * 4 + b)) << 16);
#pragma unroll
  for (int i = 0; i < 4; i++) {
#pragma unroll
    for (int r = 0; r < 4; r++) {
      const int rg = d0 + wm + i * 16 + q4 * 4 + r;   // K column (d)
#pragma unroll
      for (int j = 0; j < 4; j++) {
        const int cg = e0 + wn + j * 16 + l16;        // V column (e)
        pt[rg * 256 + cg] = __float2bfloat16(acc[i][j][r]);
      }
    }
  }
}

// ---------------- Kernel 4: Ps[b][d][e] = bf16( iv[e] * sum_chunks part[chunk][b] ) ---------
__global__ __launch_bounds__(256) void reduce_kvt(const uint32_t* __restrict__ part,
                                                  uint32_t* __restrict__ Ps,
                                                  const float* __restrict__ nsv) {
  const int flat2 = blockIdx.x * 256 + threadIdx.x;  // dword index over [4][32768]
  const int b = flat2 >> 15;
  const int off = flat2 & 32767;
  const int es = (off & 127) * 2;                    // e column pair
  float sx = 0, sy = 0;
#pragma unroll
  for (int c = 0; c < 32; c++) {
    const uint32_t u = part[(((size_t)(c * 4 + b)) << 15) + off];
    sx += bflo(u); sy += bfhi(u);
  }
  const float iv0 = rsqrtf(nsv[b * D + es] + 1e-5f);
  const float iv1 = rsqrtf(nsv[b * D + es + 1] + 1e-5f);
  Ps[flat2] = packbf(sx * iv0, sy * iv1);
}

// ---------------- Kernel 4b: MT[b][j][k] = bf16( sum_e Wo16[j,e] * Ps[b][k,e] ) -------------
__global__ __launch_bounds__(256, 2) void gemm_mt(
    const __hip_bfloat16* __restrict__ Wo16, const __hip_bfloat16* __restrict__ Ps,
    __hip_bfloat16* __restrict__ MT) {
  __shared__ __align__(16) char As[8192];
  __shared__ __align__(16) char Bs[8192];
  const int t = threadIdx.x, lane = t & 63, wid = t >> 6;
  const int wm = (wid & 1) * 64, wn = (wid >> 1) * 64;
  const int l16 = lane & 15, q4 = lane >> 4;
  const int m0 = blockIdx.x * 128, n0 = blockIdx.y * 128, b = blockIdx.z;
  const __hip_bfloat16* Bm = Ps + ((size_t)b << 16);
  floatx4 acc[4][4] = {};
  const int srow = wid * 16 + (lane >> 2);
  const int skoff = (lane & 3) * 8;
  const __hip_bfloat16* gA = Wo16 + (size_t)(m0 + srow) * D + skoff;
  const __hip_bfloat16* gB = Bm + (size_t)(n0 + srow) * D + skoff;
  char* lA = As + srow * 64 + skoff * 2;
  char* lB = Bs + srow * 64 + skoff * 2;
  for (int kt = 0; kt < 256; kt += 32) {
    gl_lds16(gA + kt, lA);
    gl_lds16(gA + kt + 64 * D, lA + 4096);
    gl_lds16(gB + kt, lB);
    gl_lds16(gB + kt + 64 * D, lB + 4096);
    __syncthreads();
    short8 af[4], bf8[4];
#pragma unroll
    for (int i = 0; i < 4; i++) {
      af[i]  = *(const short8*)(As + (wm + i * 16 + l16) * 64 + q4 * 16);
      bf8[i] = *(const short8*)(Bs + (wn + i * 16 + l16) * 64 + q4 * 16);
    }
#pragma unroll
    for (int i = 0; i < 4; i++)
#pragma unroll
      for (int j = 0; j < 4; j++)
        acc[i][j] = __builtin_amdgcn_mfma_f32_16x16x32_bf16(af[i], bf8[j], acc[i][j], 0, 0, 0);
    __syncthreads();
  }
  __hip_bfloat16* Ob = MT + ((size_t)b << 16);
#pragma unroll
  for (int j = 0; j < 4; j++) {
    const int colg = n0 + wn + j * 16 + l16;
#pragma unroll
    for (int i = 0; i < 4; i++) {
      const int rowg = m0 + wm + i * 16 + q4 * 4;
#pragma unroll
      for (int r = 0; r < 4; r++)
        Ob[(size_t)(rowg + r) * D + colg] = __float2bfloat16(acc[i][j][r]);
    }
  }
}

// ---------------- Kernel 5: out = q_rot @ MT^T + bo  (fp32 out to d_out) --------------------
__global__ __launch_bounds__(256, 2) void gemm_out(
    const __hip_bfloat16* __restrict__ A, const __hip_bfloat16* __restrict__ Pm,
    const float* __restrict__ bo, float* __restrict__ Og) {
  __shared__ __align__(16) char As[8192];
  __shared__ __align__(16) char Bs[8192];
  const int t = threadIdx.x, lane = t & 63, wid = t >> 6;
  const int wm = (wid & 1) * 64, wn = (wid >> 1) * 64;
  const int l16 = lane & 15, q4 = lane >> 4;
  const int m0 = blockIdx.x * 128, n0 = blockIdx.y * 128;
  const int b = m0 >> 13;
  const __hip_bfloat16* W = Pm + ((size_t)b << 16);
  floatx4 acc[4][4] = {};
  const int srow = wid * 16 + (lane >> 2);
  const int skoff = (lane & 3) * 8;
  const __hip_bfloat16* gA = A + (size_t)(m0 + srow) * D + skoff;
  const __hip_bfloat16* gB = W + (size_t)(n0 + srow) * D + skoff;
  char* lA = As + srow * 64 + skoff * 2;
  char* lB = Bs + srow * 64 + skoff * 2;
  for (int kt = 0; kt < 256; kt += 32) {
    gl_lds16(gA + kt, lA);
    gl_lds16(gA + kt + 64 * D, lA + 4096);
    gl_lds16(gB + kt, lB);
    gl_lds16(gB + kt + 64 * D, lB + 4096);
    __syncthreads();
    short8 af[4], bf8[4];
#pragma unroll
    for (int i = 0; i < 4; i++) {
      af[i]  = *(const short8*)(As + (wm + i * 16 + l16) * 64 + q4 * 16);
      bf8[i] = *(const short8*)(Bs + (wn + i * 16 + l16) * 64 + q4 * 16);
    }
#pragma unroll
    for (int i = 0; i < 4; i++)
#pragma unroll
      for (int j = 0; j < 4; j++)
        acc[i][j] = __builtin_amdgcn_mfma_f32_16x16x32_bf16(af[i], bf8[j], acc[i][j], 0, 0, 0);
    __syncthreads();
  }
#pragma unroll
  for (int j = 0; j < 4; j++) {
    const int colg = n0 + wn + j * 16 + l16;
    const float bb = bo[colg];
#pragma unroll
    for (int i = 0; i < 4; i++) {
      const int rowg = m0 + wm + i * 16 + q4 * 4;
#pragma unroll
      for (int r = 0; r < 4; r++)
        Og[(size_t)(rowg + r) * D + colg] = acc[i][j][r] + bb;
    }
  }
}

extern "C" void kernel_launch(void* const* d_in, const int* in_sizes, int n_in,
                              void* d_out, int out_size, void* d_ws, size_t ws_size,
                              hipStream_t stream) {
  const float* phi    = (const float*)d_in[0];
  const float* coords = (const float*)d_in[1];
  const float* wts    = (const float*)d_in[2];
  const float* bq     = (const float*)d_in[4];
  const float* bk     = (const float*)d_in[6];
  const float* bv     = (const float*)d_in[8];
  const float* Wo     = (const float*)d_in[9];
  const float* bo     = (const float*)d_in[10];
  const float* lift   = (const float*)d_in[11];

  char* ws = (char*)d_ws;
  __hip_bfloat16* W16   = (__hip_bfloat16*)(ws + 16777216);    // 4 x 128 KiB (Wq,Wk,Wv,Wo)
  const size_t QOFF = 17301504;
  const size_t SZ = (size_t)MTOT * D * 2;  // 16 MiB per bf16 buffer
  __hip_bfloat16* Qb = (__hip_bfloat16*)(ws + QOFF);
  __hip_bfloat16* Kb = (__hip_bfloat16*)(ws + QOFF + SZ);      // row-major [tok][d]
  __hip_bfloat16* Vb = (__hip_bfloat16*)(ws + QOFF + 2 * SZ);  // row-major [tok][d]
  const size_t NOFF = QOFF + 3 * SZ;
  float* nsk = (float*)(ws + NOFF);
  float* nsv = (float*)(ws + NOFF + 4096);
  __hip_bfloat16* part = (__hip_bfloat16*)(ws + NOFF + 8192);                 // 16 MiB bf16
  __hip_bfloat16* Ps   = (__hip_bfloat16*)(ws + NOFF + 8192 + 16777216);      // 512 KiB
  __hip_bfloat16* MT   = (__hip_bfloat16*)(ws + NOFF + 8192 + 16777216 + 524288);  // 512 KiB

  convert_w<<<512, 256, 0, stream>>>((const float*)d_in[3], (const float*)d_in[5],
                                     (const float*)d_in[7], Wo,
                                     (uint32_t*)W16, (float2*)(ws + NOFF));
  gemm_qkv<<<1536, 256, 0, stream>>>(phi, W16, bq, bk, bv, coords, wts, lift,
                                     Qb, Kb, Vb, nsk, nsv);
  kpoint<<<1024, 256, 0, stream>>>(Kb, coords, wts, lift, nsk);
  gemm_tn<<<512, 256, 0, stream>>>(Kb, Vb, part);
  reduce_kvt<<<512, 256, 0, stream>>>((const uint32_t*)part, (uint32_t*)Ps, nsv);
  gemm_mt<<<dim3(2, 2, 4), 256, 0, stream>>>(W16 + 3 * W_E, Ps, MT);
  gemm_out<<<dim3(256, 2), 256, 0, stream>>>(Qb, MT, bo, (float*)d_out);
}

// Round 9
// 174.352 us; speedup vs baseline: 1.0769x; 1.0217x over previous
//
#include <hip/hip_runtime.h>
#include <hip/hip_bf16.h>
#include <stdint.h>

#define DEV __device__ __forceinline__

typedef short short8 __attribute__((ext_vector_type(8)));
typedef float floatx4 __attribute__((ext_vector_type(4)));

constexpr int D = 256;
constexpr int NTOK = 8192;
constexpr int MTOT = 4 * NTOK;  // 32768 rows total

DEV void gl_lds16(const void* g, void* l) {
  __builtin_amdgcn_global_load_lds(
      (const __attribute__((address_space(1))) void*)g,
      (__attribute__((address_space(3))) void*)l, 16, 0, 0);
}

DEV float bflo(uint32_t u) { return __uint_as_float(u << 16); }
DEV float bfhi(uint32_t u) { return __uint_as_float(u & 0xffff0000u); }
DEV uint32_t packbf(float a, float b) {
  uint16_t xa = __builtin_bit_cast(uint16_t, __float2bfloat16(a));
  uint16_t xb = __builtin_bit_cast(uint16_t, __float2bfloat16(b));
  return (uint32_t)xa | ((uint32_t)xb << 16);
}

constexpr int PHI_E = MTOT * D;          // 8388608
constexpr int W_E = D * D;               // 65536

// ---------------- Kernel 0: fp32 -> bf16 conversion of phi, Wq, Wk, Wv, Wo + ns zeroing -----
// r8 post-mortem: gemm_qkv was L3-BW-bound on fp32 phi re-read x6 (~200MB through L3 at
// ~4.7TB/s = the 43us). Converting phi ONCE halves the re-read bytes and enables
// global_load_lds A-staging (no VGPR round-trip / packbf VALU in the GEMM).
__global__ __launch_bounds__(256) void convert(
    const float* __restrict__ phi, const float* __restrict__ Wq,
    const float* __restrict__ Wk, const float* __restrict__ Wv,
    const float* __restrict__ Wo,
    uint32_t* __restrict__ dst, float2* __restrict__ nszero) {
  if (blockIdx.x == 0) {
    const float2 z = {0.f, 0.f};
#pragma unroll
    for (int k = 0; k < 4; k++) nszero[k * 256 + threadIdx.x] = z;
  }
  const int idx2 = blockIdx.x * 256 + threadIdx.x;  // pair index
  const int e0 = idx2 * 2;
  float2 v;
  if (e0 < PHI_E) {
    v = ((const float2*)phi)[idx2];
  } else {
    int r = e0 - PHI_E;
    if (r < W_E) v = ((const float2*)Wq)[r >> 1];
    else if (r < 2 * W_E) v = ((const float2*)Wk)[(r - W_E) >> 1];
    else if (r < 3 * W_E) v = ((const float2*)Wv)[(r - 2 * W_E) >> 1];
    else v = ((const float2*)Wo)[(r - 3 * W_E) >> 1];
  }
  dst[idx2] = packbf(v.x, v.y);
}

// ---------------- Kernel 1: fused QKV GEMM, 128x(64+64 paired cols) tile per block ----------
// r8's high-occupancy tile (acc[4][4], VGPR 64, 4-5 blocks/CU) + bf16 phi via gl_lds16.
// Column pair (c, c+128) kept inside the block so Q-rotary stays local.
__global__ __launch_bounds__(256, 4) void gemm_qkv(
    const __hip_bfloat16* __restrict__ phi,
    const __hip_bfloat16* __restrict__ W16,
    const float* __restrict__ bq, const float* __restrict__ bk, const float* __restrict__ bv,
    const float* __restrict__ coords, const float* __restrict__ wts,
    const float* __restrict__ lift,
    __hip_bfloat16* __restrict__ Qb, __hip_bfloat16* __restrict__ Kb,
    __hip_bfloat16* __restrict__ Vb, float* __restrict__ nsk, float* __restrict__ nsv) {
  __shared__ __align__(16) char As[8192];
  __shared__ __align__(16) char Bs[8192];
  const int t = threadIdx.x, lane = t & 63, wid = t >> 6;
  const int wm = (wid & 1) * 64;         // row offset
  const int wn = (wid >> 1) * 32;        // colpair offset within 64
  const int l16 = lane & 15, q4 = lane >> 4;
  // XCD swizzle: the 6 blocks (3 mats x 2 col-halves) of one m0 adjacent -> phi L2-reused x6
  const int bid = blockIdx.x;
  const int g = (bid & 7) * 192 + (bid >> 3);
  const int sub = g % 6;
  const int mat = sub >> 1;
  const int nc0 = (sub & 1) * 64;        // colpair base: cols nc0.. and nc0+128..
  const int m0 = (g / 6) * 128;
  const __hip_bfloat16* W = W16 + (size_t)mat * W_E;
  const float* bias = (mat == 0) ? bq : (mat == 1) ? bk : bv;
  __hip_bfloat16* Out = (mat == 0) ? Qb : (mat == 1) ? Kb : Vb;

  floatx4 acc[4][4] = {};

  const int srow = wid * 16 + (lane >> 2);          // 0..63
  const int skoff = (lane & 3) * 8;
  const __hip_bfloat16* gA = phi + (size_t)(m0 + srow) * D + skoff;
  const __hip_bfloat16* gB = W + (size_t)(nc0 + srow) * D + skoff;
  char* lA = As + srow * 64 + skoff * 2;
  char* lB = Bs + srow * 64 + skoff * 2;

  for (int kt = 0; kt < 256; kt += 32) {
    gl_lds16(gA + kt, lA);
    gl_lds16(gA + kt + 64 * D, lA + 4096);
    gl_lds16(gB + kt, lB);
    gl_lds16(gB + kt + 128 * D, lB + 4096);
    __syncthreads();
    short8 af[4], bf4[4];
#pragma unroll
    for (int i = 0; i < 4; i++)
      af[i] = *(const short8*)(As + (wm + i * 16 + l16) * 64 + q4 * 16);
#pragma unroll
    for (int j = 0; j < 4; j++) {
      const int brow = (j >> 1) * 64 + wn + (j & 1) * 16 + l16;  // lo rows 0..63, hi 64..127
      bf4[j] = *(const short8*)(Bs + brow * 64 + q4 * 16);
    }
#pragma unroll
    for (int i = 0; i < 4; i++)
#pragma unroll
      for (int j = 0; j < 4; j++)
        acc[i][j] = __builtin_amdgcn_mfma_f32_16x16x32_bf16(af[i], bf4[j], acc[i][j], 0, 0, 0);
    __syncthreads();
  }

  float bcol[4];
#pragma unroll
  for (int j = 0; j < 4; j++)
    bcol[j] = bias[nc0 + wn + (j & 1) * 16 + (j >> 1) * 128 + l16];

  if (mat == 0) {
    float lx[2], ly[2], lz[2];
#pragma unroll
    for (int jj = 0; jj < 2; jj++) {
      const int c = nc0 + wn + jj * 16 + l16;
      lx[jj] = lift[c * 3 + 0]; ly[jj] = lift[c * 3 + 1]; lz[jj] = lift[c * 3 + 2];
    }
#pragma unroll
    for (int i = 0; i < 4; i++) {
#pragma unroll
      for (int r = 0; r < 4; r++) {
        const int row = m0 + wm + i * 16 + q4 * 4 + r;
        const float cx = coords[row * 3 + 0];
        const float cy = coords[row * 3 + 1];
        const float cz = coords[row * 3 + 2];
#pragma unroll
        for (int jj = 0; jj < 2; jj++) {
          const int c = nc0 + wn + jj * 16 + l16;
          const float p = cx * lx[jj] + cy * ly[jj] + cz * lz[jj];
          float s, cs;
          __sincosf(p, &s, &cs);
          const float f1 = acc[i][jj][r] + bcol[jj];
          const float f2 = acc[i][jj + 2][r] + bcol[jj + 2];
          Out[(size_t)row * D + c]       = __float2bfloat16(f1 * cs - f2 * s);
          Out[(size_t)row * D + c + 128] = __float2bfloat16(f1 * s + f2 * cs);
        }
      }
    }
  } else {
    const int b = m0 >> 13;
    float* ns = (mat == 1) ? nsk : nsv;
    float colsum[4] = {};
#pragma unroll
    for (int i = 0; i < 4; i++) {
#pragma unroll
      for (int r = 0; r < 4; r++) {
        const int row = m0 + wm + i * 16 + q4 * 4 + r;
        const float w = wts[row];
#pragma unroll
        for (int j = 0; j < 4; j++) {
          const int col = nc0 + wn + (j & 1) * 16 + (j >> 1) * 128 + l16;
          const float psi = acc[i][j][r] + bcol[j];
          Out[(size_t)row * D + col] = __float2bfloat16(psi);
          colsum[j] += w * psi * psi;
        }
      }
    }
#pragma unroll
    for (int j = 0; j < 4; j++) {
      float s = colsum[j];
      s += __shfl_xor(s, 16);
      s += __shfl_xor(s, 32);
      if (q4 == 0) {
        const int col = nc0 + wn + (j & 1) * 16 + (j >> 1) * 128 + l16;
        atomicAdd(&ns[b * D + col], s);
      }
    }
  }
}

// ---------------- Kernel 2: K pointwise (norm + rotary + weight), in-place on row-major K ---
// 1024 blocks for TLP.
__global__ __launch_bounds__(256) void kpoint(
    __hip_bfloat16* __restrict__ Kb, const float* __restrict__ coords,
    const float* __restrict__ wts, const float* __restrict__ lift,
    const float* __restrict__ nsk) {
  const int t = threadIdx.x;
  const int j = t & 63, rloc = t >> 6;
  const int r0 = blockIdx.x * 32;
  const int b = r0 >> 13;
  const int j0 = 2 * j, j1 = 2 * j + 1;
  const float lx0 = lift[j0 * 3 + 0], ly0 = lift[j0 * 3 + 1], lz0 = lift[j0 * 3 + 2];
  const float lx1 = lift[j1 * 3 + 0], ly1 = lift[j1 * 3 + 1], lz1 = lift[j1 * 3 + 2];
  const int nb = b * D;
  const float ik0 = rsqrtf(nsk[nb + j0] + 1e-5f);
  const float ik1 = rsqrtf(nsk[nb + j1] + 1e-5f);
  const float ik2 = rsqrtf(nsk[nb + 128 + j0] + 1e-5f);
  const float ik3 = rsqrtf(nsk[nb + 128 + j1] + 1e-5f);
  uint32_t* K32 = (uint32_t*)Kb;
#pragma unroll
  for (int it = 0; it < 8; it++) {
    const size_t row = (size_t)r0 + it * 4 + rloc;
    const float cx = coords[row * 3 + 0];
    const float cy = coords[row * 3 + 1];
    const float cz = coords[row * 3 + 2];
    const float p0 = cx * lx0 + cy * ly0 + cz * lz0;
    const float p1 = cx * lx1 + cy * ly1 + cz * lz1;
    float s0, c0, s1, c1;
    __sincosf(p0, &s0, &c0);
    __sincosf(p1, &s1, &c1);
    const float w = wts[row];
    const size_t base = row * 128;
    const uint32_t klo = K32[base + j], khi = K32[base + 64 + j];
    const float k1a = bflo(klo) * ik0, k1b = bfhi(klo) * ik1;
    const float k2a = bflo(khi) * ik2, k2b = bfhi(khi) * ik3;
    K32[base + j]      = packbf((k1a * c0 - k2a * s0) * w, (k1b * c1 - k2b * s1) * w);
    K32[base + 64 + j] = packbf((k1a * s0 + k2a * c0) * w, (k1b * s1 + k2b * c1) * w);
  }
}

// ---------------- Kernel 3: part[chunk][b] partial K^T V, transposed-LDS MFMA ---------------
// r1-proven config: 32 chunks x 256 tokens, 1-D grid 512 with XCD swizzle,
// bit-surgery staging into 80B-padded [e][token] LDS rows (ds_read_b128 fragments).
__global__ __launch_bounds__(256, 2) void gemm_tn(
    const __hip_bfloat16* __restrict__ Kwb, const __hip_bfloat16* __restrict__ Vb,
    __hip_bfloat16* __restrict__ part) {
  __shared__ __align__(16) char Asm[128 * 80];
  __shared__ __align__(16) char Bsm[128 * 80];
  const int t = threadIdx.x, lane = t & 63, wid = t >> 6;
  const int wm = (wid & 1) * 64, wn = (wid >> 1) * 64;
  const int l16 = lane & 15, q4 = lane >> 4;
  const int bid = blockIdx.x;
  const int g = (bid & 7) * 64 + (bid >> 3);
  const int ed = g & 3, rest = g >> 2;
  const int chunk = rest & 31, b = rest >> 5;
  const int d0 = (ed >> 1) * 128, e0 = (ed & 1) * 128;
  const uint32_t* A32 = (const uint32_t*)Kwb;
  const uint32_t* B32 = (const uint32_t*)Vb;
  const int s_np = (((t & 3) | ((t >> 6) << 2)) ^ ((t >> 4) & 3));  // 0..15
  const int s_e2lo = (t >> 2) & 15;                                  // + 16*r -> 0..63
  floatx4 acc[4][4] = {};
  for (int nt = 0; nt < 256; nt += 32) {
    const int nbase = chunk * 256 + nt;
    const size_t tokbase = ((size_t)b * NTOK + nbase + 2 * s_np) * 128;
#pragma unroll
    for (int r = 0; r < 4; r++) {
      const int e2 = s_e2lo + r * 16;
      {
        const uint32_t a0 = A32[tokbase + (d0 >> 1) + e2];
        const uint32_t a1 = A32[tokbase + 128 + (d0 >> 1) + e2];
        *(uint32_t*)(Asm + (2 * e2) * 80 + 4 * s_np)     = (a0 & 0xffffu) | (a1 << 16);
        *(uint32_t*)(Asm + (2 * e2 + 1) * 80 + 4 * s_np) = (a0 >> 16) | (a1 & 0xffff0000u);
      }
      {
        const uint32_t b0 = B32[tokbase + (e0 >> 1) + e2];
        const uint32_t b1 = B32[tokbase + 128 + (e0 >> 1) + e2];
        *(uint32_t*)(Bsm + (2 * e2) * 80 + 4 * s_np)     = (b0 & 0xffffu) | (b1 << 16);
        *(uint32_t*)(Bsm + (2 * e2 + 1) * 80 + 4 * s_np) = (b0 >> 16) | (b1 & 0xffff0000u);
      }
    }
    __syncthreads();
    short8 af[4], bf8[4];
#pragma unroll
    for (int i = 0; i < 4; i++) {
      af[i]  = *(const short8*)(Asm + (wm + i * 16 + l16) * 80 + q4 * 16);
      bf8[i] = *(const short8*)(Bsm + (wn + i * 16 + l16) * 80 + q4 * 16);
    }
#pragma unroll
    for (int i = 0; i < 4; i++)
#pragma unroll
      for (int j = 0; j < 4; j++)
        acc[i][j] = __builtin_amdgcn_mfma_f32_16x16x32_bf16(af[i], bf8[j], acc[i][j], 0, 0, 0);
    __syncthreads();
  }
  __hip_bfloat16* pt = part + (((size_t)(chunk * 4 + b)) << 16);
#pragma unroll
  for (int i = 0; i < 4; i++) {
#pragma unroll
    for (int r = 0; r < 4; r++) {
      const int rg = d0 + wm + i * 16 + q4 * 4 + r;   // K column (d)
#pragma unroll
      for (int j = 0; j < 4; j++) {
        const int cg = e0 + wn + j * 16 + l16;        // V column (e)
        pt[rg * 256 + cg] = __float2bfloat16(acc[i][j][r]);
      }
    }
  }
}

// ---------------- Kernel 4: Ps[b][d][e] = bf16( iv[e] * sum_chunks part[chunk][b] ) ---------
__global__ __launch_bounds__(256) void reduce_kvt(const uint32_t* __restrict__ part,
                                                  uint32_t* __restrict__ Ps,
                                                  const float* __restrict__ nsv) {
  const int flat2 = blockIdx.x * 256 + threadIdx.x;  // dword index over [4][32768]
  const int b = flat2 >> 15;
  const int off = flat2 & 32767;
  const int es = (off & 127) * 2;                    // e column pair
  float sx = 0, sy = 0;
#pragma unroll
  for (int c = 0; c < 32; c++) {
    const uint32_t u = part[(((size_t)(c * 4 + b)) << 15) + off];
    sx += bflo(u); sy += bfhi(u);
  }
  const float iv0 = rsqrtf(nsv[b * D + es] + 1e-5f);
  const float iv1 = rsqrtf(nsv[b * D + es + 1] + 1e-5f);
  Ps[flat2] = packbf(sx * iv0, sy * iv1);
}

// ---------------- Kernel 4b: MT[b][j][k] = bf16( sum_e Wo16[j,e] * Ps[b][k,e] ) -------------
__global__ __launch_bounds__(256, 2) void gemm_mt(
    const __hip_bfloat16* __restrict__ Wo16, const __hip_bfloat16* __restrict__ Ps,
    __hip_bfloat16* __restrict__ MT) {
  __shared__ __align__(16) char As[8192];
  __shared__ __align__(16) char Bs[8192];
  const int t = threadIdx.x, lane = t & 63, wid = t >> 6;
  const int wm = (wid & 1) * 64, wn = (wid >> 1) * 64;
  const int l16 = lane & 15, q4 = lane >> 4;
  const int m0 = blockIdx.x * 128, n0 = blockIdx.y * 128, b = blockIdx.z;
  const __hip_bfloat16* Bm = Ps + ((size_t)b << 16);
  floatx4 acc[4][4] = {};
  const int srow = wid * 16 + (lane >> 2);
  const int skoff = (lane & 3) * 8;
  const __hip_bfloat16* gA = Wo16 + (size_t)(m0 + srow) * D + skoff;
  const __hip_bfloat16* gB = Bm + (size_t)(n0 + srow) * D + skoff;
  char* lA = As + srow * 64 + skoff * 2;
  char* lB = Bs + srow * 64 + skoff * 2;
  for (int kt = 0; kt < 256; kt += 32) {
    gl_lds16(gA + kt, lA);
    gl_lds16(gA + kt + 64 * D, lA + 4096);
    gl_lds16(gB + kt, lB);
    gl_lds16(gB + kt + 64 * D, lB + 4096);
    __syncthreads();
    short8 af[4], bf8[4];
#pragma unroll
    for (int i = 0; i < 4; i++) {
      af[i]  = *(const short8*)(As + (wm + i * 16 + l16) * 64 + q4 * 16);
      bf8[i] = *(const short8*)(Bs + (wn + i * 16 + l16) * 64 + q4 * 16);
    }
#pragma unroll
    for (int i = 0; i < 4; i++)
#pragma unroll
      for (int j = 0; j < 4; j++)
        acc[i][j] = __builtin_amdgcn_mfma_f32_16x16x32_bf16(af[i], bf8[j], acc[i][j], 0, 0, 0);
    __syncthreads();
  }
  __hip_bfloat16* Ob = MT + ((size_t)b << 16);
#pragma unroll
  for (int j = 0; j < 4; j++) {
    const int colg = n0 + wn + j * 16 + l16;
#pragma unroll
    for (int i = 0; i < 4; i++) {
      const int rowg = m0 + wm + i * 16 + q4 * 4;
#pragma unroll
      for (int r = 0; r < 4; r++)
        Ob[(size_t)(rowg + r) * D + colg] = __float2bfloat16(acc[i][j][r]);
    }
  }
}

// ---------------- Kernel 5: out = q_rot @ MT^T + bo  (fp32 out to d_out) --------------------
__global__ __launch_bounds__(256, 2) void gemm_out(
    const __hip_bfloat16* __restrict__ A, const __hip_bfloat16* __restrict__ Pm,
    const float* __restrict__ bo, float* __restrict__ Og) {
  __shared__ __align__(16) char As[8192];
  __shared__ __align__(16) char Bs[8192];
  const int t = threadIdx.x, lane = t & 63, wid = t >> 6;
  const int wm = (wid & 1) * 64, wn = (wid >> 1) * 64;
  const int l16 = lane & 15, q4 = lane >> 4;
  const int m0 = blockIdx.x * 128, n0 = blockIdx.y * 128;
  const int b = m0 >> 13;
  const __hip_bfloat16* W = Pm + ((size_t)b << 16);
  floatx4 acc[4][4] = {};
  const int srow = wid * 16 + (lane >> 2);
  const int skoff = (lane & 3) * 8;
  const __hip_bfloat16* gA = A + (size_t)(m0 + srow) * D + skoff;
  const __hip_bfloat16* gB = W + (size_t)(n0 + srow) * D + skoff;
  char* lA = As + srow * 64 + skoff * 2;
  char* lB = Bs + srow * 64 + skoff * 2;
  for (int kt = 0; kt < 256; kt += 32) {
    gl_lds16(gA + kt, lA);
    gl_lds16(gA + kt + 64 * D, lA + 4096);
    gl_lds16(gB + kt, lB);
    gl_lds16(gB + kt + 64 * D, lB + 4096);
    __syncthreads();
    short8 af[4], bf8[4];
#pragma unroll
    for (int i = 0; i < 4; i++) {
      af[i]  = *(const short8*)(As + (wm + i * 16 + l16) * 64 + q4 * 16);
      bf8[i] = *(const short8*)(Bs + (wn + i * 16 + l16) * 64 + q4 * 16);
    }
#pragma unroll
    for (int i = 0; i < 4; i++)
#pragma unroll
      for (int j = 0; j < 4; j++)
        acc[i][j] = __builtin_amdgcn_mfma_f32_16x16x32_bf16(af[i], bf8[j], acc[i][j], 0, 0, 0);
    __syncthreads();
  }
#pragma unroll
  for (int j = 0; j < 4; j++) {
    const int colg = n0 + wn + j * 16 + l16;
    const float bb = bo[colg];
#pragma unroll
    for (int i = 0; i < 4; i++) {
      const int rowg = m0 + wm + i * 16 + q4 * 4;
#pragma unroll
      for (int r = 0; r < 4; r++)
        Og[(size_t)(rowg + r) * D + colg] = acc[i][j][r] + bb;
    }
  }
}

extern "C" void kernel_launch(void* const* d_in, const int* in_sizes, int n_in,
                              void* d_out, int out_size, void* d_ws, size_t ws_size,
                              hipStream_t stream) {
  const float* phi    = (const float*)d_in[0];
  const float* coords = (const float*)d_in[1];
  const float* wts    = (const float*)d_in[2];
  const float* bq     = (const float*)d_in[4];
  const float* bk     = (const float*)d_in[6];
  const float* bv     = (const float*)d_in[8];
  const float* Wo     = (const float*)d_in[9];
  const float* bo     = (const float*)d_in[10];
  const float* lift   = (const float*)d_in[11];

  char* ws = (char*)d_ws;
  __hip_bfloat16* phi16 = (__hip_bfloat16*)ws;                 // 16 MiB
  __hip_bfloat16* W16   = (__hip_bfloat16*)(ws + 16777216);    // 4 x 128 KiB (Wq,Wk,Wv,Wo)
  const size_t QOFF = 17301504;
  const size_t SZ = (size_t)MTOT * D * 2;  // 16 MiB per bf16 buffer
  __hip_bfloat16* Qb = (__hip_bfloat16*)(ws + QOFF);
  __hip_bfloat16* Kb = (__hip_bfloat16*)(ws + QOFF + SZ);      // row-major [tok][d]
  __hip_bfloat16* Vb = (__hip_bfloat16*)(ws + QOFF + 2 * SZ);  // row-major [tok][d]
  const size_t NOFF = QOFF + 3 * SZ;
  float* nsk = (float*)(ws + NOFF);
  float* nsv = (float*)(ws + NOFF + 4096);
  __hip_bfloat16* part = (__hip_bfloat16*)(ws + NOFF + 8192);                 // 16 MiB bf16
  __hip_bfloat16* Ps   = (__hip_bfloat16*)(ws + NOFF + 8192 + 16777216);      // 512 KiB
  __hip_bfloat16* MT   = (__hip_bfloat16*)(ws + NOFF + 8192 + 16777216 + 524288);  // 512 KiB

  convert<<<16896, 256, 0, stream>>>(phi, (const float*)d_in[3], (const float*)d_in[5],
                                     (const float*)d_in[7], Wo,
                                     (uint32_t*)ws, (float2*)(ws + NOFF));
  gemm_qkv<<<1536, 256, 0, stream>>>(phi16, W16, bq, bk, bv, coords, wts, lift,
                                     Qb, Kb, Vb, nsk, nsv);
  kpoint<<<1024, 256, 0, stream>>>(Kb, coords, wts, lift, nsk);
  gemm_tn<<<512, 256, 0, stream>>>(Kb, Vb, part);
  reduce_kvt<<<512, 256, 0, stream>>>((const uint32_t*)part, (uint32_t*)Ps, nsv);
  gemm_mt<<<dim3(2, 2, 4), 256, 0, stream>>>(W16 + 3 * W_E, Ps, MT);
  gemm_out<<<dim3(256, 2), 256, 0, stream>>>(Qb, MT, bo, (float*)d_out);
}